// Round 6
// baseline (369.017 us; speedup 1.0000x reference)
//
#include <hip/hip_runtime.h>
#include <stdint.h>

// Problem constants (reference: B=2, S=2048, D=1024, H=16, DK=64)
#define B_  2
#define S_  2048
#define D_  1024
#define H_  16
#define DK_ 64
#define PERHEAD (S_ * DK_)  // 131072 elems per (b,h)

// exp(x*0.125) = exp2(x * 0.125*log2(e))
#define EXP2SCALE 0.18033688011112042f

typedef __attribute__((ext_vector_type(8))) short short8;   // 8 bf16 = 4 VGPRs (MFMA A/B frag)
typedef __attribute__((ext_vector_type(4))) float floatx4;  // MFMA C/D frag

#define MFMA16(a, b, c) __builtin_amdgcn_mfma_f32_16x16x32_bf16((a), (b), (c), 0, 0, 0)

// async global->LDS, 16B per lane (used only in the projection GEMMs)
__device__ __forceinline__ void gload_lds16(const void* g, void* lds) {
  __builtin_amdgcn_global_load_lds(
      (__attribute__((address_space(1))) void*)(void*)g,
      (__attribute__((address_space(3))) void*)lds, 16, 0, 0);
}

__device__ __forceinline__ unsigned short f2bf(float f) {
  union { float f; unsigned int u; } v;
  v.f = f;
  unsigned int r = v.u + 0x7fffu + ((v.u >> 16) & 1u);
  return (unsigned short)(r >> 16);
}

// pack two positive f32 into two bf16 (round-half-up: +0x8000 then take hi16 via v_perm)
__device__ __forceinline__ unsigned int pack_bf16_rhu(float e0, float e1) {
  unsigned int u0 = __float_as_uint(e0) + 0x8000u;
  unsigned int u1 = __float_as_uint(e1) + 0x8000u;
  return __builtin_amdgcn_perm(u1, u0, 0x07060302);  // {u1.hi16, u0.hi16}
}

// ---------------- batched casts fp32 -> bf16 (one launch for 3 inputs / 4 weights) ----
__global__ void cast3_f32_bf16(const float* __restrict__ a0, const float* __restrict__ a1,
                               const float* __restrict__ a2,
                               unsigned short* __restrict__ o0, unsigned short* __restrict__ o1,
                               unsigned short* __restrict__ o2, int n4) {
  const float* in = (blockIdx.z == 0) ? a0 : (blockIdx.z == 1) ? a1 : a2;
  unsigned short* out = (blockIdx.z == 0) ? o0 : (blockIdx.z == 1) ? o1 : o2;
  int i = blockIdx.x * 256 + threadIdx.x;
  if (i < n4) {
    float4 f = ((const float4*)in)[i];
    uint2 p;
    p.x = (unsigned int)f2bf(f.x) | ((unsigned int)f2bf(f.y) << 16);
    p.y = (unsigned int)f2bf(f.z) | ((unsigned int)f2bf(f.w) << 16);
    ((uint2*)out)[i] = p;
  }
}
__global__ void cast4_f32_bf16(const float* __restrict__ a0, const float* __restrict__ a1,
                               const float* __restrict__ a2, const float* __restrict__ a3,
                               unsigned short* __restrict__ o0, unsigned short* __restrict__ o1,
                               unsigned short* __restrict__ o2, unsigned short* __restrict__ o3,
                               int n4) {
  const float* in = (blockIdx.z == 0) ? a0 : (blockIdx.z == 1) ? a1 : (blockIdx.z == 2) ? a2 : a3;
  unsigned short* out = (blockIdx.z == 0) ? o0 : (blockIdx.z == 1) ? o1 : (blockIdx.z == 2) ? o2 : o3;
  int i = blockIdx.x * 256 + threadIdx.x;
  if (i < n4) {
    float4 f = ((const float4*)in)[i];
    uint2 p;
    p.x = (unsigned int)f2bf(f.x) | ((unsigned int)f2bf(f.y) << 16);
    p.y = (unsigned int)f2bf(f.z) | ((unsigned int)f2bf(f.w) << 16);
    ((uint2*)out)[i] = p;
  }
}

// Fragment-ordered layouts (16x16x32 MFMA operand fragments; one frag = 16 rows x
// 32 k x bf16 = 512 elems = 64 lane-ordered 16B chunks; chunk L = row(L&15),
// k = (L>>4)*8..+7). Reader: ds/global _b128 at base + lane*16 -> conflict-free.
//
// Qf/Kf per (b,h): frag(sblk = s>>4, ks = dk>>5):  idx = sblk*2 + ks
// Vf    per (b,h): frag(kblk = key>>5, db = dk>>4): idx = kblk*4 + db  (rows = dk)

// ---------------- shared GEMM core: 128x128 tile, BK=32, 4 waves each 64x64 ----------
__device__ __forceinline__ void gemm_core(const unsigned short* __restrict__ A,
                                          const unsigned short* __restrict__ Bw,
                                          unsigned short* lA, unsigned short* lB,
                                          int m0, int n0, int tid, int lane, int wave,
                                          floatx4 acc[4][4]) {
  const int wm = (wave >> 1) * 64;
  const int wn = (wave & 1) * 64;
  for (int k0 = 0; k0 < D_; k0 += 32) {
#pragma unroll
    for (int l = 0; l < 2; ++l) {
      int c = l * 256 + tid;
      int row = c >> 2, cb = (c & 3) * 16;
      const char* ga = (const char*)A + ((size_t)(m0 + row) * D_ + k0) * 2 + cb;
      gload_lds16(ga, (char*)lA + (size_t)(l * 256 + wave * 64) * 16);
      const char* gb = (const char*)Bw + ((size_t)(n0 + row) * D_ + k0) * 2 + cb;
      gload_lds16(gb, (char*)lB + (size_t)(l * 256 + wave * 64) * 16);
    }
    __syncthreads();
    short8 af[4], bf_[4];
#pragma unroll
    for (int mt = 0; mt < 4; ++mt)
      af[mt] = *(const short8*)&lA[(wm + mt * 16 + (lane & 15)) * 32 + (lane >> 4) * 8];
#pragma unroll
    for (int nt = 0; nt < 4; ++nt)
      bf_[nt] = *(const short8*)&lB[(wn + nt * 16 + (lane & 15)) * 32 + (lane >> 4) * 8];
#pragma unroll
    for (int mt = 0; mt < 4; ++mt)
#pragma unroll
      for (int nt = 0; nt < 4; ++nt)
        acc[mt][nt] = MFMA16(af[mt], bf_[nt], acc[mt][nt]);
    __syncthreads();
  }
}

// ---------------- fused QKV projection: z selects (A, W, Out, epilogue) ----------------
__launch_bounds__(256, 2)
__global__ void gemm_qkv(const unsigned short* __restrict__ qi, const unsigned short* __restrict__ ki,
                         const unsigned short* __restrict__ vi,
                         const unsigned short* __restrict__ Wq, const unsigned short* __restrict__ Wk,
                         const unsigned short* __restrict__ Wv,
                         unsigned short* __restrict__ Qf, unsigned short* __restrict__ Kf,
                         unsigned short* __restrict__ Vf) {
  __shared__ unsigned short lA[128 * 32];
  __shared__ unsigned short lB[128 * 32];
  const int z = blockIdx.z;
  const unsigned short* A  = (z == 0) ? qi : (z == 1) ? ki : vi;
  const unsigned short* Bw = (z == 0) ? Wq : (z == 1) ? Wk : Wv;
  unsigned short* O        = (z == 0) ? Qf : (z == 1) ? Kf : Vf;
  const int tid = threadIdx.x, lane = tid & 63, wave = tid >> 6;
  const int m0 = blockIdx.y * 128, n0 = blockIdx.x * 128;
  const int wm = (wave >> 1) * 64, wn = (wave & 1) * 64;

  floatx4 acc[4][4] = {};
  gemm_core(A, Bw, lA, lB, m0, n0, tid, lane, wave, acc);

  if (z < 2) {  // Qf/Kf fragment layout
#pragma unroll
    for (int mt = 0; mt < 4; ++mt)
#pragma unroll
      for (int nt = 0; nt < 4; ++nt)
#pragma unroll
        for (int r = 0; r < 4; ++r) {
          int row = m0 + wm + mt * 16 + (lane >> 4) * 4 + r;  // token
          int col = n0 + wn + nt * 16 + (lane & 15);          // e
          int b = row >> 11, s = row & (S_ - 1);
          int h = col >> 6,  dk = col & 63;
          size_t base = (size_t)(b * H_ + h) * PERHEAD;
          int frag = (s >> 4) * 2 + (dk >> 5);
          int lp = (s & 15) | (((dk >> 3) & 3) << 4);
          O[base + (size_t)frag * 512 + lp * 8 + (dk & 7)] = f2bf(acc[mt][nt][r]);
        }
  } else {  // Vf fragment layout (rows = dk, k = key)
#pragma unroll
    for (int mt = 0; mt < 4; ++mt)
#pragma unroll
      for (int nt = 0; nt < 4; ++nt) {
        int row0 = m0 + wm + mt * 16 + (lane >> 4) * 4;  // 4 consecutive keys
        int col  = n0 + wn + nt * 16 + (lane & 15);
        int b = row0 >> 11, key0 = row0 & (S_ - 1);
        int h = col >> 6,   dk = col & 63;
        size_t base = (size_t)(b * H_ + h) * PERHEAD;
        int frag = (key0 >> 5) * 4 + (dk >> 4);
        int lp = (dk & 15) | (((key0 >> 3) & 3) << 4);
        unsigned long long pk =
            (unsigned long long)f2bf(acc[mt][nt][0]) |
            ((unsigned long long)f2bf(acc[mt][nt][1]) << 16) |
            ((unsigned long long)f2bf(acc[mt][nt][2]) << 32) |
            ((unsigned long long)f2bf(acc[mt][nt][3]) << 48);
        *(unsigned long long*)&O[base + (size_t)frag * 512 + lp * 8 + (key0 & 7)] = pk;
      }
  }
}

// ---------------- output projection: fp32 row-major ----------------
__launch_bounds__(256, 2)
__global__ void gemm_out(const unsigned short* __restrict__ A, const unsigned short* __restrict__ Bw,
                         float* __restrict__ O) {
  __shared__ unsigned short lA[128 * 32];
  __shared__ unsigned short lB[128 * 32];
  const int tid = threadIdx.x, lane = tid & 63, wave = tid >> 6;
  const int m0 = blockIdx.y * 128, n0 = blockIdx.x * 128;
  const int wm = (wave >> 1) * 64, wn = (wave & 1) * 64;
  floatx4 acc[4][4] = {};
  gemm_core(A, Bw, lA, lB, m0, n0, tid, lane, wave, acc);
#pragma unroll
  for (int mt = 0; mt < 4; ++mt)
#pragma unroll
    for (int nt = 0; nt < 4; ++nt)
#pragma unroll
      for (int r = 0; r < 4; ++r) {
        int row = m0 + wm + mt * 16 + (lane >> 4) * 4 + r;
        int col = n0 + wn + nt * 16 + (lane & 15);
        O[(size_t)row * D_ + col] = acc[mt][nt][r];
      }
}

// ---------------- Pass 1: Zl[b,q,k] = fp16( log2( sum_h exp2(s*C) ) ) ----------------
// 128q x 64k tiles (grid 32x16x2 = 1024 blocks, 4/CU). No LDS, no barriers.
// Head-level SW pipeline: head h+1's Q(4)+K(8) fragments are issued while head h's
// MFMA+exp chain executes -> global-load latency fully hidden.
// Wave w owns q rows [q0 + w*32, +32).
struct ZFrag { short8 q[4]; short8 k[8]; };  // 48 VGPRs

__device__ __forceinline__ void load_zfrag(ZFrag& f, const short8* qp, const short8* kp) {
  f.q[0] = qp[0];   f.q[1] = qp[64];
  f.q[2] = qp[128]; f.q[3] = qp[192];
#pragma unroll
  for (int kb = 0; kb < 4; ++kb) {
    f.k[kb * 2]     = kp[kb * 128];
    f.k[kb * 2 + 1] = kp[kb * 128 + 64];
  }
}

__launch_bounds__(256, 3)
__global__ void compute_z(const unsigned short* __restrict__ Qf,
                          const unsigned short* __restrict__ Kf,
                          unsigned short* __restrict__ Zl) {
  const int tid = threadIdx.x, lane = tid & 63, wave = tid >> 6;
  const int k0 = blockIdx.x * 64, q0 = blockIdx.y * 128, b = blockIdx.z;

  floatx4 zacc[2][4] = {};
  const short8* qp = (const short8*)Qf + (size_t)b * H_ * (PERHEAD / 8)
                     + ((q0 >> 4) + wave * 2) * 128 + lane;
  const short8* kp = (const short8*)Kf + (size_t)b * H_ * (PERHEAD / 8)
                     + (k0 >> 4) * 128 + lane;

  ZFrag zf[2];
  load_zfrag(zf[0], qp, kp);
  qp += PERHEAD / 8; kp += PERHEAD / 8;

#pragma unroll 2
  for (int h = 0; h < H_; ++h) {
    ZFrag& cur = zf[h & 1];
    if (h != H_ - 1) {
      load_zfrag(zf[(h + 1) & 1], qp, kp);
      qp += PERHEAD / 8; kp += PERHEAD / 8;
    }
#pragma unroll
    for (int kb = 0; kb < 4; ++kb) {
      floatx4 s0 = {}, s1 = {};
      s0 = MFMA16(cur.q[0], cur.k[kb * 2], s0);
      s0 = MFMA16(cur.q[1], cur.k[kb * 2 + 1], s0);
      s1 = MFMA16(cur.q[2], cur.k[kb * 2], s1);
      s1 = MFMA16(cur.q[3], cur.k[kb * 2 + 1], s1);
#pragma unroll
      for (int r = 0; r < 4; ++r) {
        zacc[0][kb][r] += exp2f(s0[r] * EXP2SCALE);
        zacc[1][kb][r] += exp2f(s1[r] * EXP2SCALE);
      }
    }
  }

#pragma unroll
  for (int sq = 0; sq < 2; ++sq)
#pragma unroll
    for (int kb = 0; kb < 4; ++kb)
#pragma unroll
      for (int r = 0; r < 4; ++r) {
        int q = q0 + wave * 32 + sq * 16 + (lane >> 4) * 4 + r;
        int k = k0 + kb * 16 + (lane & 15);
        union { _Float16 h; unsigned short u; } cv;
        cv.h = (_Float16)log2f(zacc[sq][kb][r]);
        Zl[((size_t)b * S_ + q) * S_ + k] = cv.u;
      }
}

// ---------------- Pass 2: x^T = exp2(s*C - Lz) @ V ----------------
// Block = (q-tile 64, h, b). S computed TRANSPOSED (m=key, n=q). Two 64-key tiles
// per barrier epoch; P double-buffered -> 1 barrier/epoch. Epoch-level SW pipeline:
// epoch i+1's K/V/Z fragments issue at the top of epoch i (ping-pong register sets)
// so global-load latency is hidden behind a full epoch of MFMA+exp+barrier.
struct PFrag {
  short8 k0, k1, k2, k3;  // K frags: tileA ks0/ks1, tileB ks0/ks1
  short8 v0, v1, v2, v3;  // V frags: tileA db=wave k0/k1... tileB
  uint2 zA[4], zB[4];     // Lz fp16 x4 per qb, tiles A/B
};

__device__ __forceinline__ void load_pfrag(PFrag& f, const short8* kp, const short8* vp,
                                           const unsigned short* zp) {
  f.k0 = kp[0];   f.k1 = kp[64];
  f.k2 = kp[512]; f.k3 = kp[576];
  f.v0 = vp[0];   f.v1 = vp[256];
  f.v2 = vp[512]; f.v3 = vp[768];
#pragma unroll
  for (int qb = 0; qb < 4; ++qb) {
    f.zA[qb] = *(const uint2*)(zp + (size_t)(qb * 16) * S_);
    f.zB[qb] = *(const uint2*)(zp + (size_t)(qb * 16) * S_ + 64);
  }
}

__launch_bounds__(256, 3)
__global__ void attn_pv(const unsigned short* __restrict__ Qf,
                        const unsigned short* __restrict__ Kf,
                        const unsigned short* __restrict__ Vf,
                        const unsigned short* __restrict__ Zl,
                        unsigned short* __restrict__ X) {
  __shared__ unsigned short lP[2 * 8192];  // 2 bufs x 2 tiles x 4096 ushort
  const int tid = threadIdx.x, lane = tid & 63, wave = tid >> 6;
  const int h = blockIdx.x, b = blockIdx.z;
  const int q0 = blockIdx.y * 64;

  const size_t headf = (size_t)(b * H_ + h) * (PERHEAD / 8);  // short8 units
  short8 qf[4][2];
#pragma unroll
  for (int qb = 0; qb < 4; ++qb) {
    const short8* qp = (const short8*)Qf + headf + ((q0 >> 4) + qb) * 128 + lane;
    qf[qb][0] = qp[0];
    qf[qb][1] = qp[64];
  }
  const short8* kp = (const short8*)Kf + headf + wave * 128 + lane;  // += 1024/epoch
  const short8* vp = (const short8*)Vf + headf + wave * 64 + lane;   // += 1024/epoch
  const unsigned short* zp = Zl + ((size_t)b * S_ + q0 + (lane & 15)) * S_
                             + wave * 16 + ((lane >> 4) << 2);

  // P write offset within a 4096-ushort tile region (fragment-ordered)
  const int pw_off = ((wave >> 1) << 9)
                   + (((lane & 15) | (((wave & 1) << 1 | ((lane >> 4) >> 1)) << 4)) << 3)
                   + (((lane >> 4) & 1) << 2);

  floatx4 xacc[4] = {};  // x^T[dk = wave*16 + row][q = qb*16 + col]

  PFrag fr[2];
  load_pfrag(fr[0], kp, vp, zp);
  kp += 1024; vp += 1024; zp += 128;

#pragma unroll 2
  for (int kt2 = 0; kt2 < S_ / 128; ++kt2) {
    PFrag& cur = fr[kt2 & 1];
    if (kt2 != S_ / 128 - 1) {  // guard: last prefetch would run past Zl (end of ws)
      load_pfrag(fr[(kt2 + 1) & 1], kp, vp, zp);
      kp += 1024; vp += 1024; zp += 128;
    }
    const int buf = (kt2 & 1) << 13;  // 8192 ushort per buffer

    // tile A: S^T, exp2(fma), P -> lP[buf + 0]
    {
      floatx4 sacc[4] = {};
#pragma unroll
      for (int qb = 0; qb < 4; ++qb) {
        sacc[qb] = MFMA16(cur.k0, qf[qb][0], sacc[qb]);
        sacc[qb] = MFMA16(cur.k1, qf[qb][1], sacc[qb]);
      }
#pragma unroll
      for (int qb = 0; qb < 4; ++qb) {
        union { uint2 v; _Float16 hv[4]; } za; za.v = cur.zA[qb];
        float e0 = exp2f(fmaf(sacc[qb][0], EXP2SCALE, -(float)za.hv[0]));
        float e1 = exp2f(fmaf(sacc[qb][1], EXP2SCALE, -(float)za.hv[1]));
        float e2 = exp2f(fmaf(sacc[qb][2], EXP2SCALE, -(float)za.hv[2]));
        float e3 = exp2f(fmaf(sacc[qb][3], EXP2SCALE, -(float)za.hv[3]));
        uint2 p;
        p.x = pack_bf16_rhu(e0, e1);
        p.y = pack_bf16_rhu(e2, e3);
        *(uint2*)&lP[buf + (qb << 10) + pw_off] = p;
      }
    }
    // tile B: S^T, exp2(fma), P -> lP[buf + 4096]
    {
      floatx4 sacc[4] = {};
#pragma unroll
      for (int qb = 0; qb < 4; ++qb) {
        sacc[qb] = MFMA16(cur.k2, qf[qb][0], sacc[qb]);
        sacc[qb] = MFMA16(cur.k3, qf[qb][1], sacc[qb]);
      }
#pragma unroll
      for (int qb = 0; qb < 4; ++qb) {
        union { uint2 v; _Float16 hv[4]; } zb; zb.v = cur.zB[qb];
        float e0 = exp2f(fmaf(sacc[qb][0], EXP2SCALE, -(float)zb.hv[0]));
        float e1 = exp2f(fmaf(sacc[qb][1], EXP2SCALE, -(float)zb.hv[1]));
        float e2 = exp2f(fmaf(sacc[qb][2], EXP2SCALE, -(float)zb.hv[2]));
        float e3 = exp2f(fmaf(sacc[qb][3], EXP2SCALE, -(float)zb.hv[3]));
        uint2 p;
        p.x = pack_bf16_rhu(e0, e1);
        p.y = pack_bf16_rhu(e2, e3);
        *(uint2*)&lP[buf + 4096 + (qb << 10) + pw_off] = p;
      }
    }
    __syncthreads();

    // PV for both tiles
#pragma unroll
    for (int qb = 0; qb < 4; ++qb) {
      short8 pA0 = *(const short8*)&lP[buf + (qb << 10) + (lane << 3)];
      short8 pA1 = *(const short8*)&lP[buf + (qb << 10) + 512 + (lane << 3)];
      short8 pB0 = *(const short8*)&lP[buf + 4096 + (qb << 10) + (lane << 3)];
      short8 pB1 = *(const short8*)&lP[buf + 4096 + (qb << 10) + 512 + (lane << 3)];
      xacc[qb] = MFMA16(cur.v0, pA0, xacc[qb]);
      xacc[qb] = MFMA16(cur.v1, pA1, xacc[qb]);
      xacc[qb] = MFMA16(cur.v2, pB0, xacc[qb]);
      xacc[qb] = MFMA16(cur.v3, pB1, xacc[qb]);
    }
  }

  // epilogue: transpose x^T -> x via padded LDS, then coalesced 16B stores
  __syncthreads();
  unsigned short* lX = lP;  // 64 rows(q) x 72 (dk padded)
#pragma unroll
  for (int qb = 0; qb < 4; ++qb)
#pragma unroll
    for (int r = 0; r < 4; ++r) {
      int q  = qb * 16 + (lane & 15);
      int dk = wave * 16 + (lane >> 4) * 4 + r;
      lX[q * 72 + dk] = f2bf(xacc[qb][r]);
    }
  __syncthreads();
  {
    int q = tid >> 2, cg = (tid & 3) * 16;
    short8 v0 = *(const short8*)&lX[q * 72 + cg];
    short8 v1 = *(const short8*)&lX[q * 72 + cg + 8];
    unsigned short* o = X + (size_t)(b * S_ + q0 + q) * D_ + h * DK_ + cg;
    *(short8*)&o[0] = v0;
    *(short8*)&o[8] = v1;
  }
}

// ---------------- launch ----------------
extern "C" void kernel_launch(void* const* d_in, const int* in_sizes, int n_in,
                              void* d_out, int out_size, void* d_ws, size_t ws_size,
                              hipStream_t stream) {
  const float* qi = (const float*)d_in[0];
  const float* ki = (const float*)d_in[1];
  const float* vi = (const float*)d_in[2];
  // d_in[3] = mask: reference discards masked_fill result -> unused
  const float* Wq = (const float*)d_in[4];
  const float* Wk = (const float*)d_in[5];
  const float* Wv = (const float*)d_in[6];
  const float* Wo = (const float*)d_in[7];

  const size_t NT = (size_t)B_ * S_ * D_;  // 4,194,304
  const size_t NW = (size_t)D_ * D_;       // 1,048,576

  unsigned short* w = (unsigned short*)d_ws;
  unsigned short* qi_bf = w; w += NT;
  unsigned short* ki_bf = w; w += NT;
  unsigned short* vi_bf = w; w += NT;
  unsigned short* Wq_bf = w; w += NW;
  unsigned short* Wk_bf = w; w += NW;
  unsigned short* Wv_bf = w; w += NW;
  unsigned short* Wo_bf = w; w += NW;
  unsigned short* Qf = w; w += NT;  // fragment-ordered per (b,h)
  unsigned short* Kf = w; w += NT;
  unsigned short* Vf = w; w += NT;
  unsigned short* Xb = w; w += NT;  // [b,s,e] row-major bf16
  unsigned short* Zl = w;           // [b,q,k] fp16 log2(Z), 16 MiB

  {
    int n4 = (int)(NT / 4);   // 1048576 -> 4096 blocks
    cast3_f32_bf16<<<dim3((n4 + 255) / 256, 1, 3), 256, 0, stream>>>(
        qi, ki, vi, qi_bf, ki_bf, vi_bf, n4);
    int n4w = (int)(NW / 4);  // 262144 -> 1024 blocks
    cast4_f32_bf16<<<dim3((n4w + 255) / 256, 1, 4), 256, 0, stream>>>(
        Wq, Wk, Wv, Wo, Wq_bf, Wk_bf, Wv_bf, Wo_bf, n4w);
  }

  gemm_qkv<<<dim3(D_ / 128, (B_ * S_) / 128, 3), 256, 0, stream>>>(
      qi_bf, ki_bf, vi_bf, Wq_bf, Wk_bf, Wv_bf, Qf, Kf, Vf);

  compute_z<<<dim3(S_ / 64, S_ / 128, B_), 256, 0, stream>>>(Qf, Kf, Zl);
  attn_pv<<<dim3(H_, S_ / 64, B_), 256, 0, stream>>>(Qf, Kf, Vf, Zl, Xb);

  gemm_out<<<dim3(D_ / 128, (B_ * S_) / 128), 256, 0, stream>>>(Xb, Wo_bf, (float*)d_out);
}

// Round 7
// 311.880 us; speedup vs baseline: 1.1832x; 1.1832x over previous
//
#include <hip/hip_runtime.h>
#include <stdint.h>

// Problem constants (reference: B=2, S=2048, D=1024, H=16, DK=64)
#define B_  2
#define S_  2048
#define D_  1024
#define H_  16
#define DK_ 64
#define PERHEAD (S_ * DK_)  // 131072 elems per (b,h)

// exp(x*0.125) = exp2(x * 0.125*log2(e))
#define EXP2SCALE 0.18033688011112042f

typedef __attribute__((ext_vector_type(8))) short short8;   // 8 bf16 = 4 VGPRs (MFMA A/B frag)
typedef __attribute__((ext_vector_type(4))) float floatx4;  // MFMA C/D frag

#define MFMA16(a, b, c) __builtin_amdgcn_mfma_f32_16x16x32_bf16((a), (b), (c), 0, 0, 0)

// async global->LDS, 16B per lane (used only in the projection GEMMs)
__device__ __forceinline__ void gload_lds16(const void* g, void* lds) {
  __builtin_amdgcn_global_load_lds(
      (__attribute__((address_space(1))) void*)(void*)g,
      (__attribute__((address_space(3))) void*)lds, 16, 0, 0);
}

__device__ __forceinline__ unsigned short f2bf(float f) {
  union { float f; unsigned int u; } v;
  v.f = f;
  unsigned int r = v.u + 0x7fffu + ((v.u >> 16) & 1u);
  return (unsigned short)(r >> 16);
}

// pack two positive f32 into two bf16 (round-half-up: +0x8000 then take hi16 via v_perm)
__device__ __forceinline__ unsigned int pack_bf16_rhu(float e0, float e1) {
  unsigned int u0 = __float_as_uint(e0) + 0x8000u;
  unsigned int u1 = __float_as_uint(e1) + 0x8000u;
  return __builtin_amdgcn_perm(u1, u0, 0x07060302);  // {u1.hi16, u0.hi16}
}

// ---------------- batched casts fp32 -> bf16 (one launch for 3 inputs / 4 weights) ----
__global__ void cast3_f32_bf16(const float* __restrict__ a0, const float* __restrict__ a1,
                               const float* __restrict__ a2,
                               unsigned short* __restrict__ o0, unsigned short* __restrict__ o1,
                               unsigned short* __restrict__ o2, int n4) {
  const float* in = (blockIdx.z == 0) ? a0 : (blockIdx.z == 1) ? a1 : a2;
  unsigned short* out = (blockIdx.z == 0) ? o0 : (blockIdx.z == 1) ? o1 : o2;
  int i = blockIdx.x * 256 + threadIdx.x;
  if (i < n4) {
    float4 f = ((const float4*)in)[i];
    uint2 p;
    p.x = (unsigned int)f2bf(f.x) | ((unsigned int)f2bf(f.y) << 16);
    p.y = (unsigned int)f2bf(f.z) | ((unsigned int)f2bf(f.w) << 16);
    ((uint2*)out)[i] = p;
  }
}
__global__ void cast4_f32_bf16(const float* __restrict__ a0, const float* __restrict__ a1,
                               const float* __restrict__ a2, const float* __restrict__ a3,
                               unsigned short* __restrict__ o0, unsigned short* __restrict__ o1,
                               unsigned short* __restrict__ o2, unsigned short* __restrict__ o3,
                               int n4) {
  const float* in = (blockIdx.z == 0) ? a0 : (blockIdx.z == 1) ? a1 : (blockIdx.z == 2) ? a2 : a3;
  unsigned short* out = (blockIdx.z == 0) ? o0 : (blockIdx.z == 1) ? o1 : (blockIdx.z == 2) ? o2 : o3;
  int i = blockIdx.x * 256 + threadIdx.x;
  if (i < n4) {
    float4 f = ((const float4*)in)[i];
    uint2 p;
    p.x = (unsigned int)f2bf(f.x) | ((unsigned int)f2bf(f.y) << 16);
    p.y = (unsigned int)f2bf(f.z) | ((unsigned int)f2bf(f.w) << 16);
    ((uint2*)out)[i] = p;
  }
}

// Fragment-ordered layouts (16x16x32 MFMA operand fragments; one frag = 16 rows x
// 32 k x bf16 = 512 elems = 64 lane-ordered 16B chunks; chunk L = row(L&15),
// k = (L>>4)*8..+7). Reader: ds/global _b128 at base + lane*16 -> conflict-free.
//
// Qf/Kf per (b,h): frag(sblk = s>>4, ks = dk>>5):  idx = sblk*2 + ks
// Vf    per (b,h): frag(kblk = key>>5, db = dk>>4): idx = kblk*4 + db  (rows = dk)

// ---------------- shared GEMM core: 128x128 tile, BK=32, 4 waves each 64x64 ----------
__device__ __forceinline__ void gemm_core(const unsigned short* __restrict__ A,
                                          const unsigned short* __restrict__ Bw,
                                          unsigned short* lA, unsigned short* lB,
                                          int m0, int n0, int tid, int lane, int wave,
                                          floatx4 acc[4][4]) {
  const int wm = (wave >> 1) * 64;
  const int wn = (wave & 1) * 64;
  for (int k0 = 0; k0 < D_; k0 += 32) {
#pragma unroll
    for (int l = 0; l < 2; ++l) {
      int c = l * 256 + tid;
      int row = c >> 2, cb = (c & 3) * 16;
      const char* ga = (const char*)A + ((size_t)(m0 + row) * D_ + k0) * 2 + cb;
      gload_lds16(ga, (char*)lA + (size_t)(l * 256 + wave * 64) * 16);
      const char* gb = (const char*)Bw + ((size_t)(n0 + row) * D_ + k0) * 2 + cb;
      gload_lds16(gb, (char*)lB + (size_t)(l * 256 + wave * 64) * 16);
    }
    __syncthreads();
    short8 af[4], bf_[4];
#pragma unroll
    for (int mt = 0; mt < 4; ++mt)
      af[mt] = *(const short8*)&lA[(wm + mt * 16 + (lane & 15)) * 32 + (lane >> 4) * 8];
#pragma unroll
    for (int nt = 0; nt < 4; ++nt)
      bf_[nt] = *(const short8*)&lB[(wn + nt * 16 + (lane & 15)) * 32 + (lane >> 4) * 8];
#pragma unroll
    for (int mt = 0; mt < 4; ++mt)
#pragma unroll
      for (int nt = 0; nt < 4; ++nt)
        acc[mt][nt] = MFMA16(af[mt], bf_[nt], acc[mt][nt]);
    __syncthreads();
  }
}

// ---------------- fused QKV projection: z selects (A, W, Out, epilogue) ----------------
__launch_bounds__(256, 2)
__global__ void gemm_qkv(const unsigned short* __restrict__ qi, const unsigned short* __restrict__ ki,
                         const unsigned short* __restrict__ vi,
                         const unsigned short* __restrict__ Wq, const unsigned short* __restrict__ Wk,
                         const unsigned short* __restrict__ Wv,
                         unsigned short* __restrict__ Qf, unsigned short* __restrict__ Kf,
                         unsigned short* __restrict__ Vf) {
  __shared__ unsigned short lA[128 * 32];
  __shared__ unsigned short lB[128 * 32];
  const int z = blockIdx.z;
  const unsigned short* A  = (z == 0) ? qi : (z == 1) ? ki : vi;
  const unsigned short* Bw = (z == 0) ? Wq : (z == 1) ? Wk : Wv;
  unsigned short* O        = (z == 0) ? Qf : (z == 1) ? Kf : Vf;
  const int tid = threadIdx.x, lane = tid & 63, wave = tid >> 6;
  const int m0 = blockIdx.y * 128, n0 = blockIdx.x * 128;
  const int wm = (wave >> 1) * 64, wn = (wave & 1) * 64;

  floatx4 acc[4][4] = {};
  gemm_core(A, Bw, lA, lB, m0, n0, tid, lane, wave, acc);

  if (z < 2) {  // Qf/Kf fragment layout
#pragma unroll
    for (int mt = 0; mt < 4; ++mt)
#pragma unroll
      for (int nt = 0; nt < 4; ++nt)
#pragma unroll
        for (int r = 0; r < 4; ++r) {
          int row = m0 + wm + mt * 16 + (lane >> 4) * 4 + r;  // token
          int col = n0 + wn + nt * 16 + (lane & 15);          // e
          int b = row >> 11, s = row & (S_ - 1);
          int h = col >> 6,  dk = col & 63;
          size_t base = (size_t)(b * H_ + h) * PERHEAD;
          int frag = (s >> 4) * 2 + (dk >> 5);
          int lp = (s & 15) | (((dk >> 3) & 3) << 4);
          O[base + (size_t)frag * 512 + lp * 8 + (dk & 7)] = f2bf(acc[mt][nt][r]);
        }
  } else {  // Vf fragment layout (rows = dk, k = key)
#pragma unroll
    for (int mt = 0; mt < 4; ++mt)
#pragma unroll
      for (int nt = 0; nt < 4; ++nt) {
        int row0 = m0 + wm + mt * 16 + (lane >> 4) * 4;  // 4 consecutive keys
        int col  = n0 + wn + nt * 16 + (lane & 15);
        int b = row0 >> 11, key0 = row0 & (S_ - 1);
        int h = col >> 6,   dk = col & 63;
        size_t base = (size_t)(b * H_ + h) * PERHEAD;
        int frag = (key0 >> 5) * 4 + (dk >> 4);
        int lp = (dk & 15) | (((key0 >> 3) & 3) << 4);
        unsigned long long pk =
            (unsigned long long)f2bf(acc[mt][nt][0]) |
            ((unsigned long long)f2bf(acc[mt][nt][1]) << 16) |
            ((unsigned long long)f2bf(acc[mt][nt][2]) << 32) |
            ((unsigned long long)f2bf(acc[mt][nt][3]) << 48);
        *(unsigned long long*)&O[base + (size_t)frag * 512 + lp * 8 + (key0 & 7)] = pk;
      }
  }
}

// ---------------- output projection: fp32 row-major ----------------
__launch_bounds__(256, 2)
__global__ void gemm_out(const unsigned short* __restrict__ A, const unsigned short* __restrict__ Bw,
                         float* __restrict__ O) {
  __shared__ unsigned short lA[128 * 32];
  __shared__ unsigned short lB[128 * 32];
  const int tid = threadIdx.x, lane = tid & 63, wave = tid >> 6;
  const int m0 = blockIdx.y * 128, n0 = blockIdx.x * 128;
  const int wm = (wave >> 1) * 64, wn = (wave & 1) * 64;
  floatx4 acc[4][4] = {};
  gemm_core(A, Bw, lA, lB, m0, n0, tid, lane, wave, acc);
#pragma unroll
  for (int mt = 0; mt < 4; ++mt)
#pragma unroll
    for (int nt = 0; nt < 4; ++nt)
#pragma unroll
      for (int r = 0; r < 4; ++r) {
        int row = m0 + wm + mt * 16 + (lane >> 4) * 4 + r;
        int col = n0 + wn + nt * 16 + (lane & 15);
        O[(size_t)row * D_ + col] = acc[mt][nt][r];
      }
}

// ---------------- Pass 1: Zl[b,q,k] = fp16( log2( sum_h exp2(s*C) ) ) ----------------
// 128x128 tiles (grid 16x16x2). No LDS, no barriers. Wave w owns q rows [q0+w*32).
// (round-5 version — known stable; K staged 4 frag-pairs at a time)
__launch_bounds__(256, 3)
__global__ void compute_z(const unsigned short* __restrict__ Qf,
                          const unsigned short* __restrict__ Kf,
                          unsigned short* __restrict__ Zl) {
  const int tid = threadIdx.x, lane = tid & 63, wave = tid >> 6;
  const int k0 = blockIdx.x * 128, q0 = blockIdx.y * 128, b = blockIdx.z;

  floatx4 zacc[2][8] = {};
  const short8* qbase = (const short8*)Qf + (size_t)b * H_ * (PERHEAD / 8)
                        + ((q0 >> 4) + wave * 2) * 128 + lane;
  const short8* kbase = (const short8*)Kf + (size_t)b * H_ * (PERHEAD / 8)
                        + (k0 >> 4) * 128 + lane;

#pragma unroll 1
  for (int h = 0; h < H_; ++h) {
    short8 qf0 = qbase[0], qf1 = qbase[64];    // sq=0, ks=0/1
    short8 qf2 = qbase[128], qf3 = qbase[192]; // sq=1, ks=0/1
#pragma unroll
    for (int hf = 0; hf < 2; ++hf) {
      short8 kst[4][2];
#pragma unroll
      for (int kb = 0; kb < 4; ++kb) {
        kst[kb][0] = kbase[(hf * 4 + kb) * 128];
        kst[kb][1] = kbase[(hf * 4 + kb) * 128 + 64];
      }
#pragma unroll
      for (int kb = 0; kb < 4; ++kb) {
        floatx4 s0 = {}, s1 = {};
        s0 = MFMA16(qf0, kst[kb][0], s0);
        s0 = MFMA16(qf1, kst[kb][1], s0);
        s1 = MFMA16(qf2, kst[kb][0], s1);
        s1 = MFMA16(qf3, kst[kb][1], s1);
#pragma unroll
        for (int r = 0; r < 4; ++r) {
          zacc[0][hf * 4 + kb][r] += exp2f(s0[r] * EXP2SCALE);
          zacc[1][hf * 4 + kb][r] += exp2f(s1[r] * EXP2SCALE);
        }
      }
    }
    qbase += PERHEAD / 8;
    kbase += PERHEAD / 8;
  }

#pragma unroll
  for (int sq = 0; sq < 2; ++sq)
#pragma unroll
    for (int kb = 0; kb < 8; ++kb)
#pragma unroll
      for (int r = 0; r < 4; ++r) {
        int q = q0 + wave * 32 + sq * 16 + (lane >> 4) * 4 + r;
        int k = k0 + kb * 16 + (lane & 15);
        union { _Float16 h; unsigned short u; } cv;
        cv.h = (_Float16)log2f(zacc[sq][kb][r]);
        Zl[((size_t)b * S_ + q) * S_ + k] = cv.u;
      }
}

// ---------------- Pass 2: x^T = exp2(s*C - Lz) @ V ----------------
// Block = (q-tile 64, h, b). Single 64-key tile per iteration (round-3 structure,
// best measured), P double-buffered -> 1 barrier/iter. Register-resident prefetch:
// next iteration's K(2)+V(2)+Z(4x8B) in INDIVIDUALLY-NAMED variables, rotated by
// copy at loop tail (unroll 2 -> renames). No struct arrays (r6's spilled to scratch).
__launch_bounds__(256, 3)
__global__ void attn_pv(const unsigned short* __restrict__ Qf,
                        const unsigned short* __restrict__ Kf,
                        const unsigned short* __restrict__ Vf,
                        const unsigned short* __restrict__ Zl,
                        unsigned short* __restrict__ X) {
  __shared__ unsigned short lP[2 * 4096];  // 2 bufs x (64q x 64k) fragment-ordered
  const int tid = threadIdx.x, lane = tid & 63, wave = tid >> 6;
  const int h = blockIdx.x, b = blockIdx.z;
  const int q0 = blockIdx.y * 64;

  const size_t headf = (size_t)(b * H_ + h) * (PERHEAD / 8);  // short8 units
  short8 qf[4][2];
#pragma unroll
  for (int qb = 0; qb < 4; ++qb) {
    const short8* qp = (const short8*)Qf + headf + ((q0 >> 4) + qb) * 128 + lane;
    qf[qb][0] = qp[0];
    qf[qb][1] = qp[64];
  }
  const short8* kp = (const short8*)Kf + headf + wave * 128 + lane;  // += 512/iter
  const short8* vp = (const short8*)Vf + headf + wave * 64 + lane;   // += 512/iter
  const unsigned short* zp = Zl + ((size_t)b * S_ + q0 + (lane & 15)) * S_
                             + wave * 16 + ((lane >> 4) << 2);

  // P write offset (ushort units, within one 4096 tile region): fragment-ordered
  const int pw_off = ((wave >> 1) << 9)
                   + (((lane & 15) | (((wave & 1) << 1 | ((lane >> 4) >> 1)) << 4)) << 3)
                   + (((lane >> 4) & 1) << 2);

  floatx4 xacc[4] = {};  // x^T[dk = wave*16 + row][q = qb*16 + col]

  // prologue: load iteration 0's operands
  short8 ck0 = kp[0], ck1 = kp[64];
  short8 cv0 = vp[0], cv1 = vp[256];
  uint2 cz0 = *(const uint2*)(zp);
  uint2 cz1 = *(const uint2*)(zp + (size_t)16 * S_);
  uint2 cz2 = *(const uint2*)(zp + (size_t)32 * S_);
  uint2 cz3 = *(const uint2*)(zp + (size_t)48 * S_);
  kp += 512; vp += 512; zp += 64;

#pragma unroll 2
  for (int kt = 0; kt < S_ / 64; ++kt) {
    const int buf = (kt & 1) << 12;
    // prefetch next iteration (named registers; guarded on last iter)
    short8 nk0, nk1, nv0, nv1;
    uint2 nz0, nz1, nz2, nz3;
    if (kt != S_ / 64 - 1) {
      nk0 = kp[0];  nk1 = kp[64];
      nv0 = vp[0];  nv1 = vp[256];
      nz0 = *(const uint2*)(zp);
      nz1 = *(const uint2*)(zp + (size_t)16 * S_);
      nz2 = *(const uint2*)(zp + (size_t)32 * S_);
      nz3 = *(const uint2*)(zp + (size_t)48 * S_);
      kp += 512; vp += 512; zp += 64;
    }

    // S^T tiles: m = 16 keys (wave's), n = 64 q
    floatx4 sacc[4] = {};
#pragma unroll
    for (int qb = 0; qb < 4; ++qb) {
      sacc[qb] = MFMA16(ck0, qf[qb][0], sacc[qb]);
      sacc[qb] = MFMA16(ck1, qf[qb][1], sacc[qb]);
    }
    // P = exp2(s*C - Lz) -> bf16, fragment-ordered in LDS
#pragma unroll
    for (int qb = 0; qb < 4; ++qb) {
      uint2 zz = (qb == 0) ? cz0 : (qb == 1) ? cz1 : (qb == 2) ? cz2 : cz3;
      union { uint2 v; _Float16 hv[4]; } za; za.v = zz;
      float e0 = exp2f(fmaf(sacc[qb][0], EXP2SCALE, -(float)za.hv[0]));
      float e1 = exp2f(fmaf(sacc[qb][1], EXP2SCALE, -(float)za.hv[1]));
      float e2 = exp2f(fmaf(sacc[qb][2], EXP2SCALE, -(float)za.hv[2]));
      float e3 = exp2f(fmaf(sacc[qb][3], EXP2SCALE, -(float)za.hv[3]));
      uint2 p;
      p.x = pack_bf16_rhu(e0, e1);
      p.y = pack_bf16_rhu(e2, e3);
      *(uint2*)&lP[buf + (qb << 10) + pw_off] = p;
    }
    __syncthreads();

    // x^T += V_frag @ P  (conflict-free lane*16 reads)
#pragma unroll
    for (int qb = 0; qb < 4; ++qb) {
      short8 p0 = *(const short8*)&lP[buf + (qb << 10) + (lane << 3)];
      short8 p1 = *(const short8*)&lP[buf + (qb << 10) + 512 + (lane << 3)];
      xacc[qb] = MFMA16(cv0, p0, xacc[qb]);
      xacc[qb] = MFMA16(cv1, p1, xacc[qb]);
    }

    // rotate prefetched -> current (renames under unroll)
    ck0 = nk0; ck1 = nk1; cv0 = nv0; cv1 = nv1;
    cz0 = nz0; cz1 = nz1; cz2 = nz2; cz3 = nz3;
  }

  // epilogue: transpose x^T -> x via padded LDS, then coalesced 16B stores
  __syncthreads();
  unsigned short* lX = lP;  // 64 rows(q) x 72 (dk padded)
#pragma unroll
  for (int qb = 0; qb < 4; ++qb)
#pragma unroll
    for (int r = 0; r < 4; ++r) {
      int q  = qb * 16 + (lane & 15);
      int dk = wave * 16 + (lane >> 4) * 4 + r;
      lX[q * 72 + dk] = f2bf(xacc[qb][r]);
    }
  __syncthreads();
  {
    int q = tid >> 2, cg = (tid & 3) * 16;
    short8 v0 = *(const short8*)&lX[q * 72 + cg];
    short8 v1 = *(const short8*)&lX[q * 72 + cg + 8];
    unsigned short* o = X + (size_t)(b * S_ + q0 + q) * D_ + h * DK_ + cg;
    *(short8*)&o[0] = v0;
    *(short8*)&o[8] = v1;
  }
}

// ---------------- launch ----------------
extern "C" void kernel_launch(void* const* d_in, const int* in_sizes, int n_in,
                              void* d_out, int out_size, void* d_ws, size_t ws_size,
                              hipStream_t stream) {
  const float* qi = (const float*)d_in[0];
  const float* ki = (const float*)d_in[1];
  const float* vi = (const float*)d_in[2];
  // d_in[3] = mask: reference discards masked_fill result -> unused
  const float* Wq = (const float*)d_in[4];
  const float* Wk = (const float*)d_in[5];
  const float* Wv = (const float*)d_in[6];
  const float* Wo = (const float*)d_in[7];

  const size_t NT = (size_t)B_ * S_ * D_;  // 4,194,304
  const size_t NW = (size_t)D_ * D_;       // 1,048,576

  unsigned short* w = (unsigned short*)d_ws;
  unsigned short* qi_bf = w; w += NT;
  unsigned short* ki_bf = w; w += NT;
  unsigned short* vi_bf = w; w += NT;
  unsigned short* Wq_bf = w; w += NW;
  unsigned short* Wk_bf = w; w += NW;
  unsigned short* Wv_bf = w; w += NW;
  unsigned short* Wo_bf = w; w += NW;
  unsigned short* Qf = w; w += NT;  // fragment-ordered per (b,h)
  unsigned short* Kf = w; w += NT;
  unsigned short* Vf = w; w += NT;
  unsigned short* Xb = w; w += NT;  // [b,s,e] row-major bf16
  unsigned short* Zl = w;           // [b,q,k] fp16 log2(Z), 16 MiB

  {
    int n4 = (int)(NT / 4);   // 1048576 -> 4096 blocks
    cast3_f32_bf16<<<dim3((n4 + 255) / 256, 1, 3), 256, 0, stream>>>(
        qi, ki, vi, qi_bf, ki_bf, vi_bf, n4);
    int n4w = (int)(NW / 4);  // 262144 -> 1024 blocks
    cast4_f32_bf16<<<dim3((n4w + 255) / 256, 1, 4), 256, 0, stream>>>(
        Wq, Wk, Wv, Wo, Wq_bf, Wk_bf, Wv_bf, Wo_bf, n4w);
  }

  gemm_qkv<<<dim3(D_ / 128, (B_ * S_) / 128, 3), 256, 0, stream>>>(
      qi_bf, ki_bf, vi_bf, Wq_bf, Wk_bf, Wv_bf, Qf, Kf, Vf);

  compute_z<<<dim3(S_ / 128, S_ / 128, B_), 256, 0, stream>>>(Qf, Kf, Zl);
  attn_pv<<<dim3(H_, S_ / 64, B_), 256, 0, stream>>>(Qf, Kf, Vf, Zl, Xb);

  gemm_out<<<dim3(D_ / 128, (B_ * S_) / 128), 256, 0, stream>>>(Xb, Wo_bf, (float*)d_out);
}